// Round 1
// baseline (1167.341 us; speedup 1.0000x reference)
//
#include <hip/hip_runtime.h>
#include <math.h>

#define NB 16384      // rows
#define TWO_D 8192
#define DHALF 4096

__global__ void init_acc(double* acc, unsigned long long* cnt) {
    if (threadIdx.x == 0) { *acc = 0.0; *cnt = 0ull; }
}

__global__ __launch_bounds__(256) void row_kernel(
    const float* __restrict__ outp, const float* __restrict__ gtp,
    const int* __restrict__ epoch_p,
    double* __restrict__ acc, unsigned long long* __restrict__ cnt)
{
    const int row = blockIdx.x;
    const size_t base = (size_t)row * TWO_D;
    const float4* o_r = (const float4*)(outp + base);
    const float4* o_i = (const float4*)(outp + base + DHALF);
    const float4* g_r = (const float4*)(gtp + base);
    const float4* g_i = (const float4*)(gtp + base + DHALF);
    const int tid = threadIdx.x;

    float lsum = 0.f, lmax = 0.f;
    float gv = -INFINITY; int gi = 0;   // argmax of gt_r
    float ov = -INFINITY; int oi = 0;   // argmax of out_r

    // DHALF/4 = 1024 float4 per stream; 256 threads -> 4 iterations
    for (int v = tid; v < DHALF / 4; v += 256) {
        float4 a = o_r[v];
        float4 b = o_i[v];
        float4 c = g_r[v];
        float4 d = g_i[v];
        const int jb = v * 4;
        float er, ei, s;
        #define COMP(K, AK, BK, CK, DK)                              \
            er = (CK) - (AK); ei = (DK) - (BK);                      \
            s = er * er + ei * ei;                                   \
            lsum += s; lmax = fmaxf(lmax, s);                        \
            if ((CK) > gv) { gv = (CK); gi = jb + (K); }             \
            if ((AK) > ov) { ov = (AK); oi = jb + (K); }
        COMP(0, a.x, b.x, c.x, d.x)
        COMP(1, a.y, b.y, c.y, d.y)
        COMP(2, a.z, b.z, c.z, d.z)
        COMP(3, a.w, b.w, c.w, d.w)
        #undef COMP
    }

    // wave-64 reduction
    for (int off = 32; off > 0; off >>= 1) {
        lsum += __shfl_down(lsum, off);
        lmax = fmaxf(lmax, __shfl_down(lmax, off));
        float gv2 = __shfl_down(gv, off); int gi2 = __shfl_down(gi, off);
        if (gv2 > gv || (gv2 == gv && gi2 < gi)) { gv = gv2; gi = gi2; }
        float ov2 = __shfl_down(ov, off); int oi2 = __shfl_down(oi, off);
        if (ov2 > ov || (ov2 == ov && oi2 < oi)) { ov = ov2; oi = oi2; }
    }

    __shared__ float ssum[4], smax[4], sgv[4], sov[4];
    __shared__ int   sgi[4], soi[4];
    const int wave = tid >> 6;
    if ((tid & 63) == 0) {
        ssum[wave] = lsum; smax[wave] = lmax;
        sgv[wave] = gv; sgi[wave] = gi;
        sov[wave] = ov; soi[wave] = oi;
    }
    __syncthreads();

    if (tid == 0) {
        float tsum = ssum[0], tmax = smax[0];
        float tgv = sgv[0]; int tgi = sgi[0];
        float tov = sov[0]; int toi = soi[0];
        #pragma unroll
        for (int w = 1; w < 4; ++w) {
            tsum += ssum[w];
            tmax = fmaxf(tmax, smax[w]);
            if (sgv[w] > tgv || (sgv[w] == tgv && sgi[w] < tgi)) { tgv = sgv[w]; tgi = sgi[w]; }
            if (sov[w] > tov || (sov[w] == tov && soi[w] < toi)) { tov = sov[w]; toi = soi[w]; }
        }
        const int epoch = *epoch_p;
        // 0.5 * exp(-0.2) computed in double, rounded to fp32
        const float thresh = (epoch % 10 == 0) ? 0.40936537653899909f : 0.5f;
        const bool masked = (tgi == toi) && (sqrtf(tmax) < thresh);
        if (masked) {
            atomicAdd(cnt, 1ull);
        } else {
            atomicAdd(cnt, (unsigned long long)DHALF);
            atomicAdd(acc, (double)tsum);
        }
    }
}

__global__ void finalize(const double* __restrict__ acc,
                         const unsigned long long* __restrict__ cnt,
                         float* __restrict__ outp) {
    if (threadIdx.x == 0 && blockIdx.x == 0) {
        outp[0] = (float)(*acc / (1.0 + (double)*cnt));
    }
}

extern "C" void kernel_launch(void* const* d_in, const int* in_sizes, int n_in,
                              void* d_out, int out_size, void* d_ws, size_t ws_size,
                              hipStream_t stream) {
    const float* out_p   = (const float*)d_in[0];
    const float* gt_p    = (const float*)d_in[1];
    const int*   epoch_p = (const int*)d_in[2];

    double* acc = (double*)d_ws;
    unsigned long long* cnt = (unsigned long long*)((char*)d_ws + 8);

    hipLaunchKernelGGL(init_acc, dim3(1), dim3(64), 0, stream, acc, cnt);
    hipLaunchKernelGGL(row_kernel, dim3(NB), dim3(256), 0, stream,
                       out_p, gt_p, epoch_p, acc, cnt);
    hipLaunchKernelGGL(finalize, dim3(1), dim3(64), 0, stream,
                       acc, cnt, (float*)d_out);
}